// Round 2
// baseline (4595.010 us; speedup 1.0000x reference)
//
#include <hip/hip_runtime.h>

#define DEV __device__ __forceinline__

// Problem dims (fixed)
constexpr int L = 256, NB = 64, E = 256, HH = 256, T = 9;
constexpr int WG_PER_DIR = 64;            // recurrence WGs per direction
constexpr int U_PER_WG = HH / WG_PER_DIR; // 4 units per WG

// ---- workspace layout (float offsets, after 8 KB header) ----
constexpr size_t OF_BMAT  = 0;                          // [256][2048]  w_ih^T both dirs
constexpr size_t OF_WPK   = OF_BMAT + (size_t)256*2048; // [2][256u][256k][4g]
constexpr size_t OF_BIAS  = OF_WPK + (size_t)2*256*256*4; // [2][256][4]
constexpr size_t OF_CINIT = OF_BIAS + (size_t)2*256*4;  // [2][256u][64b]
constexpr size_t OF_WOUT  = OF_CINIT + (size_t)2*256*64; // [512][12]
constexpr size_t OF_AUX   = OF_WOUT + (size_t)512*12;   // 256: [0..8] b_out, [16..24] start, [32..40] end, [48..128] trans
constexpr size_t OF_X32   = OF_AUX + 256;               // [16384][256] embedded inputs f32
constexpr size_t OF_XPROJ = OF_X32 + (size_t)16384*256; // [2][256t][256u][64b][4g]
constexpr size_t OF_HF    = OF_XPROJ + (size_t)2*256*256*64*4; // [257][256u][64b] slot t+1 = h_f(t), slot0 init
constexpr size_t OF_HB    = OF_HF + (size_t)257*256*64;        // [257], slot t = h_b(t), slot256 init
constexpr size_t OF_FEATS = OF_HB + (size_t)257*256*64; // [256t][9][64]
constexpr size_t OF_HIST  = OF_FEATS + (size_t)256*9*64; // uchar[255][9][64]

// prep segment bounds
constexpr size_t S1 = (size_t)256*2048;        // Bmat
constexpr size_t S2 = S1 + (size_t)2*256*256*4; // w_pk
constexpr size_t S3 = S2 + (size_t)2*256*4;     // bias
constexpr size_t S4 = S3 + (size_t)2*256*64;    // h_init
constexpr size_t S5 = S4 + (size_t)2*256*64;    // c_init
constexpr size_t S6 = S5 + (size_t)512*12;      // w_outP
constexpr size_t S7 = S6 + 256;                 // aux

DEV float b2f(unsigned short u) {
  union { unsigned int i; float f; } c; c.i = ((unsigned int)u) << 16; return c.f;
}
DEV float ldf(const void* p, size_t i, int isb) {
  return isb ? b2f(((const unsigned short*)p)[i]) : ((const float*)p)[i];
}
DEV float sigm(float x) { return 1.0f / (1.0f + expf(-x)); }

// ---- K0: dtype probe + zero sync flags ----
__global__ void k_probe(const void* emb, int* flag, int* cnt) {
  int tid = threadIdx.x;
  cnt[tid] = 0; cnt[tid + 256] = 0;
  if (tid == 0) {
    const unsigned short* p = (const unsigned short*)emb;
    int bad = 0;
    for (int i = 0; i < 256; ++i) {
      float f = b2f(p[i]);
      if (!(fabsf(f) < 1e6f)) bad = 1;   // NaN/huge -> really fp32 data
    }
    *flag = bad ? 0 : 1;                  // 1 = bf16 inputs
  }
}

// ---- K1: convert/pack all weights to f32 in ws ----
__global__ __launch_bounds__(256) void k_prep(
    const int* __restrict__ flag,
    const void* wihf, const void* whhf, const void* bihf, const void* bhhf,
    const void* wihb, const void* whhb, const void* bihb, const void* bhhb,
    const void* h0, const void* c0, const void* wout, const void* bout,
    const void* st, const void* en, const void* tr, float* __restrict__ F) {
  int isb = *flag;
  for (size_t i = (size_t)blockIdx.x * 256 + threadIdx.x; i < S7; i += (size_t)gridDim.x * 256) {
    if (i < S1) { // Bmat[k][n]: n = dir*1024 + u*4 + g <- w_ih[g*256+u][k]
      size_t k = i >> 11; int n = (int)(i & 2047);
      int dir = n >> 10, r = n & 1023, u = r >> 2, g = r & 3;
      const void* src = dir ? wihb : wihf;
      F[OF_BMAT + i] = ldf(src, (size_t)(g*256 + u)*256 + k, isb);
    } else if (i < S2) { // w_pk[dir][u][k][g] <- w_hh[g*256+u][k]
      size_t j = i - S1; int g = (int)(j & 3); size_t r = j >> 2;
      int k = (int)(r & 255); r >>= 8; int u = (int)(r & 255); int dir = (int)(r >> 8);
      const void* src = dir ? whhb : whhf;
      F[OF_WPK + j] = ldf(src, (size_t)(g*256 + u)*256 + k, isb);
    } else if (i < S3) { // bias_pk[dir][u][g] = b_ih + b_hh
      size_t j = i - S2; int g = (int)(j & 3); size_t r = j >> 2;
      int u = (int)(r & 255); int dir = (int)(r >> 8);
      const void* bi = dir ? bihb : bihf; const void* bh = dir ? bhhb : bhhf;
      F[OF_BIAS + j] = ldf(bi, (size_t)g*256 + u, isb) + ldf(bh, (size_t)g*256 + u, isb);
    } else if (i < S4) { // h init: [u][b] <- h0[dir][b][u]
      size_t j = i - S3; int dir = (int)(j >> 14); int r = (int)(j & 16383);
      int u = r >> 6, b = r & 63;
      float v = ldf(h0, (size_t)dir*16384 + (size_t)b*256 + u, isb);
      if (dir == 0) F[OF_HF + r] = v;               // slot 0
      else          F[OF_HB + (size_t)256*16384 + r] = v; // slot 256
    } else if (i < S5) { // c init
      size_t j = i - S4; int dir = (int)(j >> 14); int r = (int)(j & 16383);
      int u = r >> 6, b = r & 63;
      F[OF_CINIT + j] = ldf(c0, (size_t)dir*16384 + (size_t)b*256 + u, isb);
    } else if (i < S6) { // w_outP[j][tag] (stride 12) <- w_out[tag][j]
      size_t j = i - S5; int jj = (int)(j / 12); int tag = (int)(j % 12);
      F[OF_WOUT + j] = (tag < 9) ? ldf(wout, (size_t)tag*512 + jj, isb) : 0.0f;
    } else { // aux
      int j = (int)(i - S6); float v = 0.0f;
      if (j < 9) v = ldf(bout, j, isb);
      else if (j >= 16 && j < 25) v = ldf(st, j - 16, isb);
      else if (j >= 32 && j < 41) v = ldf(en, j - 32, isb);
      else if (j >= 48 && j < 129) v = ldf(tr, j - 48, isb);
      F[OF_AUX + j] = v;
    }
  }
}

// ---- K2a: embedding gather -> x32[m=(l*64+b)][k] f32 ----
__global__ __launch_bounds__(256) void k_gather(const int* __restrict__ flag,
    const int* __restrict__ sent, const void* __restrict__ emb, float* __restrict__ x32) {
  int isb = *flag;
  int g = blockIdx.x * 256 + threadIdx.x;   // 1,048,576 threads
  int m = g >> 6, q = g & 63;
  int l = m >> 6, b = m & 63;
  int row = sent[b * 256 + l];
  float4 v;
  if (isb) {
    const ushort4 s4 = ((const ushort4*)emb)[(size_t)row * 64 + q];
    v.x = b2f(s4.x); v.y = b2f(s4.y); v.z = b2f(s4.z); v.w = b2f(s4.w);
  } else {
    v = ((const float4*)emb)[(size_t)row * 64 + q];
  }
  ((float4*)x32)[(size_t)m * 64 + q] = v;
}

// ---- K2b: xproj GEMM  M=16384 N=2048 K=256 (f32), epilogue scatters to [t][u][b][g] + bias ----
__global__ __launch_bounds__(256) void k_gemm(const float* __restrict__ x32,
    const float* __restrict__ Bm, const float* __restrict__ biasPk, float* __restrict__ xproj) {
  __shared__ float As[8][128];
  __shared__ float Bs[8][128];
  int tid = threadIdx.x;
  int mTile = blockIdx.x >> 4, nTile = blockIdx.x & 15;
  int mBase = mTile * 128, nBase = nTile * 128;
  int ty = tid >> 4, tx = tid & 15;
  int ar = tid >> 1, ac = (tid & 1) * 4;
  int br = tid >> 5, bc = (tid & 31) * 4;
  float acc[8][8] = {};
  for (int k0 = 0; k0 < 256; k0 += 8) {
    float4 av = *(const float4*)(x32 + (size_t)(mBase + ar) * 256 + k0 + ac);
    float4 bv = *(const float4*)(Bm + (size_t)(k0 + br) * 2048 + nBase + bc);
    __syncthreads();
    As[ac + 0][ar] = av.x; As[ac + 1][ar] = av.y; As[ac + 2][ar] = av.z; As[ac + 3][ar] = av.w;
    *(float4*)&Bs[br][bc] = bv;
    __syncthreads();
#pragma unroll
    for (int kk = 0; kk < 8; ++kk) {
      float4 a0 = *(const float4*)&As[kk][ty * 8];
      float4 a1 = *(const float4*)&As[kk][ty * 8 + 4];
      float4 b0 = *(const float4*)&Bs[kk][tx * 8];
      float4 b1 = *(const float4*)&Bs[kk][tx * 8 + 4];
      float a[8] = {a0.x,a0.y,a0.z,a0.w,a1.x,a1.y,a1.z,a1.w};
      float bb[8] = {b0.x,b0.y,b0.z,b0.w,b1.x,b1.y,b1.z,b1.w};
#pragma unroll
      for (int i = 0; i < 8; ++i)
#pragma unroll
        for (int j = 0; j < 8; ++j) acc[i][j] = fmaf(a[i], bb[j], acc[i][j]);
    }
  }
  // epilogue: n = nBase+tx*8+j ; dir = n>>10 ; u = (n&1023)>>2 ; g = n&3
  int n0 = nBase + tx * 8;
  int dir = n0 >> 10, r0 = n0 & 1023, u0 = r0 >> 2;
  float4 bias0 = *(const float4*)(biasPk + (size_t)(dir * 256 + u0) * 4);
  float4 bias1 = *(const float4*)(biasPk + (size_t)(dir * 256 + u0 + 1) * 4);
  float* xp = xproj + ((size_t)dir << 24);
  for (int mm = 0; mm < 8; ++mm) {
    int m = mBase + ty * 8 + mm; int t = m >> 6, b = m & 63;
    float4 v0 = {acc[mm][0] + bias0.x, acc[mm][1] + bias0.y, acc[mm][2] + bias0.z, acc[mm][3] + bias0.w};
    float4 v1 = {acc[mm][4] + bias1.x, acc[mm][5] + bias1.y, acc[mm][6] + bias1.z, acc[mm][7] + bias1.w};
    *(float4*)(xp + ((size_t)(t * 256 + u0) * 64 + b) * 4) = v0;
    *(float4*)(xp + ((size_t)(t * 256 + u0 + 1) * 64 + b) * 4) = v1;
  }
}

// ---- K3: persistent BiLSTM recurrence. 128 WGs: dir = blk>>6, 4 units each.
// Cross-WG coherence via RELAXED AGENT-scope atomics only (sc-flagged ld/st,
// NO buffer_inv / buffer_wbl2 fences -> L2 stays warm for weights/xproj).
__global__ __launch_bounds__(256) void k_rec(const float* __restrict__ F,
                                             float* __restrict__ Fm, int* __restrict__ cnt) {
  __shared__ __align__(16) float lds_h[16384];   // h_prev [u 0..255][b 0..63]
  int tid = threadIdx.x;
  int blk = blockIdx.x;
  int dir = blk >> 6, wg = blk & 63;
  int u_local = tid >> 6, b = tid & 63;
  int u = wg * U_PER_WG + u_local;
  int uu = __builtin_amdgcn_readfirstlane(u);    // wave-uniform -> scalar loads of w

  const float* wrow = F + OF_WPK + ((size_t)(dir * 256 + uu)) * 1024; // [k][4]
  const float* xpd  = F + OF_XPROJ + ((size_t)dir << 24);
  float* hall = Fm + (dir == 0 ? OF_HF : OF_HB);
  int* myflags = cnt + dir * 64;                 // flags[wg] = last completed step + 1

  float c = F[OF_CINIT + (size_t)dir * 16384 + u * 64 + b];

  for (int i = 0; i < 256; ++i) {
    int t = (dir == 0) ? i : (255 - i);
    const float* hsrc = hall + (size_t)((dir == 0) ? i : (t + 1)) * 16384;
    float* hdst = hall + (size_t)((dir == 0) ? (i + 1) : t) * 16384;

    // issue xproj load for this step BEFORE the poll -> HBM latency hides
    float4 acc = *(const float4*)(xpd + ((size_t)(t * 256 + uu) * 64 + b) * 4);

    if (i > 0) {
      if (tid < 64) {   // wave 0: each lane watches one producer WG's flag
        long spins = 0;
        for (;;) {
          int v = __hip_atomic_load(&myflags[tid], __ATOMIC_RELAXED, __HIP_MEMORY_SCOPE_AGENT);
          if (__ballot(v >= i) == ~0ULL) break;
          if (++spins > (1L << 20)) break;       // safety valve
        }
      }
      __syncthreads();
    }
    // stage h_prev into LDS via coherent 8B atomic loads (bypass stale L1/L2)
    {
      unsigned long long* hs8 = (unsigned long long*)hsrc;
      unsigned long long* ls8 = (unsigned long long*)lds_h;
#pragma unroll
      for (int r = 0; r < 32; ++r) {
        int idx = r * 256 + tid;
        ls8[idx] = __hip_atomic_load(&hs8[idx], __ATOMIC_RELAXED, __HIP_MEMORY_SCOPE_AGENT);
      }
    }
    __syncthreads();

    // gates = xproj + h_prev @ w_hh^T  (i,f,g,o packed as float4 per k)
#pragma unroll 8
    for (int k = 0; k < 256; ++k) {
      float hv = lds_h[k * 64 + b];
      float4 w4 = *(const float4*)(wrow + k * 4);
      acc.x = fmaf(hv, w4.x, acc.x);
      acc.y = fmaf(hv, w4.y, acc.y);
      acc.z = fmaf(hv, w4.z, acc.z);
      acc.w = fmaf(hv, w4.w, acc.w);
    }
    c = sigm(acc.y) * c + sigm(acc.x) * tanhf(acc.z);
    float h = sigm(acc.w) * tanhf(c);
    // coherent publish of h (write-through to coherence point, no fence needed)
    __hip_atomic_store(&hdst[u * 64 + b], h, __ATOMIC_RELAXED, __HIP_MEMORY_SCOPE_AGENT);

    if (i < 255) {
      __syncthreads();  // compiler emits s_waitcnt vmcnt(0) before s_barrier:
                        // all 256 h-stores have reached the coherence point
      if (tid == 0)
        __hip_atomic_store(&myflags[wg], i + 1, __ATOMIC_RELAXED, __HIP_MEMORY_SCOPE_AGENT);
    }
  }
}

// ---- K4: feats[t][tag][b] = [hf(t), hb(t)] @ w_out^T + b_out ----
__global__ __launch_bounds__(256) void k_feats(const float* __restrict__ F, float* __restrict__ feats) {
  __shared__ float part[4][9][64];
  int t = blockIdx.x;
  int tid = threadIdx.x;
  int w = tid >> 6, b = tid & 63;
  const float* hsrc = (w < 2) ? (F + OF_HF + (size_t)(t + 1) * 16384)
                              : (F + OF_HB + (size_t)t * 16384);
  int ubase = (w & 1) * 128;
  int jglob0 = (w >> 1) * 256;
  float acc[9] = {};
  for (int jj = 0; jj < 128; ++jj) {
    int u = ubase + jj;
    float hv = hsrc[u * 64 + b];
    int j = __builtin_amdgcn_readfirstlane(jglob0 + u);
    const float* wp = F + OF_WOUT + (size_t)j * 12;
#pragma unroll
    for (int tag = 0; tag < 9; ++tag) acc[tag] = fmaf(hv, wp[tag], acc[tag]);
  }
#pragma unroll
  for (int tag = 0; tag < 9; ++tag) part[w][tag][b] = acc[tag];
  __syncthreads();
  for (int idx = tid; idx < 576; idx += 256) {
    int tag = idx >> 6, bb = idx & 63;
    float s = part[0][tag][bb] + part[1][tag][bb] + part[2][tag][bb] + part[3][tag][bb]
            + F[OF_AUX + tag];
    feats[((size_t)t * 9 + tag) * 64 + bb] = s;
  }
}

// ---- K5: CRF Viterbi decode (mask all-ones). 1 WG, 9 waves: wave=cur tag, lane=b ----
__global__ __launch_bounds__(576) void k_vit(const float* __restrict__ F,
                                             unsigned char* __restrict__ hist, int* __restrict__ out) {
  __shared__ float sc[2][9][64];
  const float* feats = F + OF_FEATS;
  const float* aux = F + OF_AUX;
  int tid = threadIdx.x;
  int cur = tid >> 6, b = tid & 63;
  float tr[9];
#pragma unroll
  for (int pv = 0; pv < 9; ++pv) tr[pv] = aux[48 + pv * 9 + cur];
  sc[0][cur][b] = aux[16 + cur] + feats[cur * 64 + b];
  __syncthreads();
  int p = 0;
  for (int t = 1; t < 256; ++t) {
    float emit = feats[((size_t)t * 9 + cur) * 64 + b];
    float best = sc[p][0][b] + tr[0]; int ba = 0;
#pragma unroll
    for (int pv = 1; pv < 9; ++pv) {
      float v = sc[p][pv][b] + tr[pv];
      if (v > best) { best = v; ba = pv; }   // strict > keeps FIRST max (jnp.argmax)
    }
    sc[p ^ 1][cur][b] = best + emit;
    hist[((size_t)(t - 1) * 9 + cur) * 64 + b] = (unsigned char)ba;
    p ^= 1;
    __syncthreads();
  }
  __threadfence();
  if (tid < 64) {
    float best = sc[p][0][tid] + aux[32]; int tag = 0;
    for (int cu = 1; cu < 9; ++cu) {
      float v = sc[p][cu][tid] + aux[32 + cu];
      if (v > best) { best = v; tag = cu; }
    }
    out[tid * 256 + 255] = tag;
    for (int pos = 254; pos >= 0; --pos) {
      tag = hist[((size_t)pos * 9 + tag) * 64 + tid];
      out[tid * 256 + pos] = tag;
    }
  }
}

extern "C" void kernel_launch(void* const* d_in, const int* in_sizes, int n_in,
                              void* d_out, int out_size, void* d_ws, size_t ws_size,
                              hipStream_t stream) {
  char* ws = (char*)d_ws;
  int* flag = (int*)ws;
  int* cnt = (int*)(ws + 64);
  float* F = (float*)(ws + 8192);
  unsigned char* hist = (unsigned char*)(F + OF_HIST);

  const int* sent = (const int*)d_in[0];
  // d_in[1] = mask: all-ones, ignored by construction.

  k_probe<<<1, 256, 0, stream>>>(d_in[2], flag, cnt);
  k_prep<<<2048, 256, 0, stream>>>(flag,
      d_in[3], d_in[4], d_in[5], d_in[6],
      d_in[7], d_in[8], d_in[9], d_in[10],
      d_in[11], d_in[12], d_in[13], d_in[14],
      d_in[15], d_in[16], d_in[17], F);
  k_gather<<<4096, 256, 0, stream>>>(flag, sent, d_in[2], F + OF_X32);
  k_gemm<<<2048, 256, 0, stream>>>(F + OF_X32, F + OF_BMAT, F + OF_BIAS, F + OF_XPROJ);
  k_rec<<<2 * WG_PER_DIR, 256, 0, stream>>>(F, F, cnt);
  k_feats<<<256, 256, 0, stream>>>(F, F + OF_FEATS);
  k_vit<<<1, 576, 0, stream>>>(F, hist, (int*)d_out);
}

// Round 4
// 3200.123 us; speedup vs baseline: 1.4359x; 1.4359x over previous
//
#include <hip/hip_runtime.h>

#define DEV __device__ __forceinline__

typedef float nfloat4 __attribute__((ext_vector_type(4)));  // native vec for nontemporal builtins

// Problem dims (fixed)
constexpr int L = 256, NB = 64, E = 256, HH = 256, T = 9;
constexpr int WG_PER_DIR = 64;            // recurrence WGs per direction
constexpr int U_PER_WG = HH / WG_PER_DIR; // 4 units per WG

// ---- workspace layout (float offsets, after 8 KB header) ----
constexpr size_t OF_BMAT  = 0;                          // [256][2048]  w_ih^T both dirs
constexpr size_t OF_WPK   = OF_BMAT + (size_t)256*2048; // [2][256u][256k][4g]
constexpr size_t OF_BIAS  = OF_WPK + (size_t)2*256*256*4; // [2][256][4]
constexpr size_t OF_CINIT = OF_BIAS + (size_t)2*256*4;  // [2][256u][64b]
constexpr size_t OF_WOUT  = OF_CINIT + (size_t)2*256*64; // [512][12]
constexpr size_t OF_AUX   = OF_WOUT + (size_t)512*12;   // 256: [0..8] b_out, [16..24] start, [32..40] end, [48..128] trans
constexpr size_t OF_X32   = OF_AUX + 256;               // [16384][256] embedded inputs f32
constexpr size_t OF_XPROJ = OF_X32 + (size_t)16384*256; // [2][256t][256u][64b][4g]
constexpr size_t OF_HF    = OF_XPROJ + (size_t)2*256*256*64*4; // [257][256u][64b] slot t+1 = h_f(t), slot0 init
constexpr size_t OF_HB    = OF_HF + (size_t)257*256*64;        // [257], slot t = h_b(t), slot256 init
constexpr size_t OF_FEATS = OF_HB + (size_t)257*256*64; // [256t][9][64]
constexpr size_t OF_HIST  = OF_FEATS + (size_t)256*9*64; // uchar[255][9][64]

// prep segment bounds
constexpr size_t S1 = (size_t)256*2048;        // Bmat
constexpr size_t S2 = S1 + (size_t)2*256*256*4; // w_pk
constexpr size_t S3 = S2 + (size_t)2*256*4;     // bias
constexpr size_t S4 = S3 + (size_t)2*256*64;    // h_init
constexpr size_t S5 = S4 + (size_t)2*256*64;    // c_init
constexpr size_t S6 = S5 + (size_t)512*12;      // w_outP
constexpr size_t S7 = S6 + 256;                 // aux

DEV float b2f(unsigned short u) {
  union { unsigned int i; float f; } c; c.i = ((unsigned int)u) << 16; return c.f;
}
DEV float ldf(const void* p, size_t i, int isb) {
  return isb ? b2f(((const unsigned short*)p)[i]) : ((const float*)p)[i];
}
DEV float sigm(float x) { return 1.0f / (1.0f + expf(-x)); }

// ---- K0: dtype probe + zero sync flags ----
__global__ void k_probe(const void* emb, int* flag, int* cnt) {
  int tid = threadIdx.x;
  cnt[tid] = 0; cnt[tid + 256] = 0;
  if (tid == 0) {
    const unsigned short* p = (const unsigned short*)emb;
    int bad = 0;
    for (int i = 0; i < 256; ++i) {
      float f = b2f(p[i]);
      if (!(fabsf(f) < 1e6f)) bad = 1;   // NaN/huge -> really fp32 data
    }
    *flag = bad ? 0 : 1;                  // 1 = bf16 inputs
  }
}

// ---- K1: convert/pack all weights to f32 in ws ----
__global__ __launch_bounds__(256) void k_prep(
    const int* __restrict__ flag,
    const void* wihf, const void* whhf, const void* bihf, const void* bhhf,
    const void* wihb, const void* whhb, const void* bihb, const void* bhhb,
    const void* h0, const void* c0, const void* wout, const void* bout,
    const void* st, const void* en, const void* tr, float* __restrict__ F) {
  int isb = *flag;
  for (size_t i = (size_t)blockIdx.x * 256 + threadIdx.x; i < S7; i += (size_t)gridDim.x * 256) {
    if (i < S1) { // Bmat[k][n]: n = dir*1024 + u*4 + g <- w_ih[g*256+u][k]
      size_t k = i >> 11; int n = (int)(i & 2047);
      int dir = n >> 10, r = n & 1023, u = r >> 2, g = r & 3;
      const void* src = dir ? wihb : wihf;
      F[OF_BMAT + i] = ldf(src, (size_t)(g*256 + u)*256 + k, isb);
    } else if (i < S2) { // w_pk[dir][u][k][g] <- w_hh[g*256+u][k]
      size_t j = i - S1; int g = (int)(j & 3); size_t r = j >> 2;
      int k = (int)(r & 255); r >>= 8; int u = (int)(r & 255); int dir = (int)(r >> 8);
      const void* src = dir ? whhb : whhf;
      F[OF_WPK + j] = ldf(src, (size_t)(g*256 + u)*256 + k, isb);
    } else if (i < S3) { // bias_pk[dir][u][g] = b_ih + b_hh
      size_t j = i - S2; int g = (int)(j & 3); size_t r = j >> 2;
      int u = (int)(r & 255); int dir = (int)(r >> 8);
      const void* bi = dir ? bihb : bihf; const void* bh = dir ? bhhb : bhhf;
      F[OF_BIAS + j] = ldf(bi, (size_t)g*256 + u, isb) + ldf(bh, (size_t)g*256 + u, isb);
    } else if (i < S4) { // h init: [u][b] <- h0[dir][b][u]
      size_t j = i - S3; int dir = (int)(j >> 14); int r = (int)(j & 16383);
      int u = r >> 6, b = r & 63;
      float v = ldf(h0, (size_t)dir*16384 + (size_t)b*256 + u, isb);
      if (dir == 0) F[OF_HF + r] = v;               // slot 0
      else          F[OF_HB + (size_t)256*16384 + r] = v; // slot 256
    } else if (i < S5) { // c init
      size_t j = i - S4; int dir = (int)(j >> 14); int r = (int)(j & 16383);
      int u = r >> 6, b = r & 63;
      F[OF_CINIT + j] = ldf(c0, (size_t)dir*16384 + (size_t)b*256 + u, isb);
    } else if (i < S6) { // w_outP[j][tag] (stride 12) <- w_out[tag][j]
      size_t j = i - S5; int jj = (int)(j / 12); int tag = (int)(j % 12);
      F[OF_WOUT + j] = (tag < 9) ? ldf(wout, (size_t)tag*512 + jj, isb) : 0.0f;
    } else { // aux
      int j = (int)(i - S6); float v = 0.0f;
      if (j < 9) v = ldf(bout, j, isb);
      else if (j >= 16 && j < 25) v = ldf(st, j - 16, isb);
      else if (j >= 32 && j < 41) v = ldf(en, j - 32, isb);
      else if (j >= 48 && j < 129) v = ldf(tr, j - 48, isb);
      F[OF_AUX + j] = v;
    }
  }
}

// ---- K2a: embedding gather -> x32[m=(l*64+b)][k] f32 ----
__global__ __launch_bounds__(256) void k_gather(const int* __restrict__ flag,
    const int* __restrict__ sent, const void* __restrict__ emb, float* __restrict__ x32) {
  int isb = *flag;
  int g = blockIdx.x * 256 + threadIdx.x;   // 1,048,576 threads
  int m = g >> 6, q = g & 63;
  int l = m >> 6, b = m & 63;
  int row = sent[b * 256 + l];
  float4 v;
  if (isb) {
    const ushort4 s4 = ((const ushort4*)emb)[(size_t)row * 64 + q];
    v.x = b2f(s4.x); v.y = b2f(s4.y); v.z = b2f(s4.z); v.w = b2f(s4.w);
  } else {
    v = ((const float4*)emb)[(size_t)row * 64 + q];
  }
  ((float4*)x32)[(size_t)m * 64 + q] = v;
}

// ---- K2b: xproj GEMM  M=16384 N=2048 K=256 (f32), epilogue scatters to [t][u][b][g] + bias ----
__global__ __launch_bounds__(256) void k_gemm(const float* __restrict__ x32,
    const float* __restrict__ Bm, const float* __restrict__ biasPk, float* __restrict__ xproj) {
  __shared__ float As[8][128];
  __shared__ float Bs[8][128];
  int tid = threadIdx.x;
  int mTile = blockIdx.x >> 4, nTile = blockIdx.x & 15;
  int mBase = mTile * 128, nBase = nTile * 128;
  int ty = tid >> 4, tx = tid & 15;
  int ar = tid >> 1, ac = (tid & 1) * 4;
  int br = tid >> 5, bc = (tid & 31) * 4;
  float acc[8][8] = {};
  for (int k0 = 0; k0 < 256; k0 += 8) {
    float4 av = *(const float4*)(x32 + (size_t)(mBase + ar) * 256 + k0 + ac);
    float4 bv = *(const float4*)(Bm + (size_t)(k0 + br) * 2048 + nBase + bc);
    __syncthreads();
    As[ac + 0][ar] = av.x; As[ac + 1][ar] = av.y; As[ac + 2][ar] = av.z; As[ac + 3][ar] = av.w;
    *(float4*)&Bs[br][bc] = bv;
    __syncthreads();
#pragma unroll
    for (int kk = 0; kk < 8; ++kk) {
      float4 a0 = *(const float4*)&As[kk][ty * 8];
      float4 a1 = *(const float4*)&As[kk][ty * 8 + 4];
      float4 b0 = *(const float4*)&Bs[kk][tx * 8];
      float4 b1 = *(const float4*)&Bs[kk][tx * 8 + 4];
      float a[8] = {a0.x,a0.y,a0.z,a0.w,a1.x,a1.y,a1.z,a1.w};
      float bb[8] = {b0.x,b0.y,b0.z,b0.w,b1.x,b1.y,b1.z,b1.w};
#pragma unroll
      for (int i = 0; i < 8; ++i)
#pragma unroll
        for (int j = 0; j < 8; ++j) acc[i][j] = fmaf(a[i], bb[j], acc[i][j]);
    }
  }
  // epilogue: n = nBase+tx*8+j ; dir = n>>10 ; u = (n&1023)>>2 ; g = n&3
  int n0 = nBase + tx * 8;
  int dir = n0 >> 10, r0 = n0 & 1023, u0 = r0 >> 2;
  float4 bias0 = *(const float4*)(biasPk + (size_t)(dir * 256 + u0) * 4);
  float4 bias1 = *(const float4*)(biasPk + (size_t)(dir * 256 + u0 + 1) * 4);
  float* xp = xproj + ((size_t)dir << 24);
  for (int mm = 0; mm < 8; ++mm) {
    int m = mBase + ty * 8 + mm; int t = m >> 6, b = m & 63;
    float4 v0 = {acc[mm][0] + bias0.x, acc[mm][1] + bias0.y, acc[mm][2] + bias0.z, acc[mm][3] + bias0.w};
    float4 v1 = {acc[mm][4] + bias1.x, acc[mm][5] + bias1.y, acc[mm][6] + bias1.z, acc[mm][7] + bias1.w};
    *(float4*)(xp + ((size_t)(t * 256 + u0) * 64 + b) * 4) = v0;
    *(float4*)(xp + ((size_t)(t * 256 + u0 + 1) * 64 + b) * 4) = v1;
  }
}

// ---- K3: persistent BiLSTM recurrence. 128 WGs: dir = blk>>6, 4 units each.
// Coherence protocol: h published via agent-scope relaxed atomic store
// (write-through to coherence point, drained by the pre-barrier vmcnt(0));
// flags via agent-scope relaxed atomics (must bypass caches to re-read).
// h STAGING uses PLAIN nontemporal vector loads: every h line is first-touch
// in this dispatch, so a plain miss fetches the written-through data; plain
// loads pipeline (16 in flight) where atomic loads serialize. nt flag keeps
// the 64 KB staging stream from flushing w_hh out of L1 every step.
__global__ __launch_bounds__(256) void k_rec(const float* __restrict__ F,
                                             float* __restrict__ Fm, int* __restrict__ cnt) {
  __shared__ __align__(16) float lds_h[16384];   // h_prev [u 0..255][b 0..63]
  int tid = threadIdx.x;
  int blk = blockIdx.x;
  int dir = blk >> 6, wg = blk & 63;
  int u_local = tid >> 6, b = tid & 63;
  int u = wg * U_PER_WG + u_local;
  int uu = __builtin_amdgcn_readfirstlane(u);    // wave-uniform -> scalar loads of w

  const float* wrow = F + OF_WPK + ((size_t)(dir * 256 + uu)) * 1024; // [k][4]
  const float* xpd  = F + OF_XPROJ + ((size_t)dir << 24);
  float* hall = Fm + (dir == 0 ? OF_HF : OF_HB);
  int* myflags = cnt + dir * 64;                 // flags[wg] = last completed step + 1

  float c = F[OF_CINIT + (size_t)dir * 16384 + u * 64 + b];

  for (int i = 0; i < 256; ++i) {
    int t = (dir == 0) ? i : (255 - i);
    const float* hsrc = hall + (size_t)((dir == 0) ? i : (t + 1)) * 16384;
    float* hdst = hall + (size_t)((dir == 0) ? (i + 1) : t) * 16384;

    // issue xproj load for this step BEFORE the poll -> HBM latency hides
    float4 acc = *(const float4*)(xpd + ((size_t)(t * 256 + uu) * 64 + b) * 4);

    if (i > 0) {
      if (tid < 64) {   // wave 0: each lane watches one producer WG's flag
        long spins = 0;
        for (;;) {
          int v = __hip_atomic_load(&myflags[tid], __ATOMIC_RELAXED, __HIP_MEMORY_SCOPE_AGENT);
          if (__ballot(v >= i) == ~0ULL) break;
          __builtin_amdgcn_s_sleep(1);           // ~64 cyc backoff, keeps fabric quiet
          if (++spins > (1L << 20)) break;       // safety valve
        }
      }
      __syncthreads();
    }
    // stage h_prev into LDS: plain nontemporal vec4 (16/thread, pipelined)
    {
      const nfloat4* hs4 = (const nfloat4*)hsrc;
      nfloat4* ls4 = (nfloat4*)lds_h;
#pragma unroll
      for (int r = 0; r < 16; ++r) {
        int idx = r * 256 + tid;
        ls4[idx] = __builtin_nontemporal_load(&hs4[idx]);
      }
    }
    __syncthreads();

    // gates = xproj + h_prev @ w_hh^T  (i,f,g,o packed as float4 per k)
#pragma unroll 8
    for (int k = 0; k < 256; ++k) {
      float hv = lds_h[k * 64 + b];
      float4 w4 = *(const float4*)(wrow + k * 4);
      acc.x = fmaf(hv, w4.x, acc.x);
      acc.y = fmaf(hv, w4.y, acc.y);
      acc.z = fmaf(hv, w4.z, acc.z);
      acc.w = fmaf(hv, w4.w, acc.w);
    }
    c = sigm(acc.y) * c + sigm(acc.x) * tanhf(acc.z);
    float h = sigm(acc.w) * tanhf(c);
    // coherent publish of h (write-through to coherence point)
    __hip_atomic_store(&hdst[u * 64 + b], h, __ATOMIC_RELAXED, __HIP_MEMORY_SCOPE_AGENT);

    if (i < 255) {
      __syncthreads();  // s_waitcnt vmcnt(0) before s_barrier: all 256 h-stores acked
      if (tid == 0)
        __hip_atomic_store(&myflags[wg], i + 1, __ATOMIC_RELAXED, __HIP_MEMORY_SCOPE_AGENT);
    }
  }
}

// ---- K4: feats[t][tag][b] = [hf(t), hb(t)] @ w_out^T + b_out ----
__global__ __launch_bounds__(256) void k_feats(const float* __restrict__ F, float* __restrict__ feats) {
  __shared__ float part[4][9][64];
  int t = blockIdx.x;
  int tid = threadIdx.x;
  int w = tid >> 6, b = tid & 63;
  const float* hsrc = (w < 2) ? (F + OF_HF + (size_t)(t + 1) * 16384)
                              : (F + OF_HB + (size_t)t * 16384);
  int ubase = (w & 1) * 128;
  int jglob0 = (w >> 1) * 256;
  float acc[9] = {};
  for (int jj = 0; jj < 128; ++jj) {
    int u = ubase + jj;
    float hv = hsrc[u * 64 + b];
    int j = __builtin_amdgcn_readfirstlane(jglob0 + u);
    const float* wp = F + OF_WOUT + (size_t)j * 12;
#pragma unroll
    for (int tag = 0; tag < 9; ++tag) acc[tag] = fmaf(hv, wp[tag], acc[tag]);
  }
#pragma unroll
  for (int tag = 0; tag < 9; ++tag) part[w][tag][b] = acc[tag];
  __syncthreads();
  for (int idx = tid; idx < 576; idx += 256) {
    int tag = idx >> 6, bb = idx & 63;
    float s = part[0][tag][bb] + part[1][tag][bb] + part[2][tag][bb] + part[3][tag][bb]
            + F[OF_AUX + tag];
    feats[((size_t)t * 9 + tag) * 64 + bb] = s;
  }
}

// ---- K5: CRF Viterbi decode (mask all-ones). 1 WG, 9 waves: wave=cur tag, lane=b ----
__global__ __launch_bounds__(576) void k_vit(const float* __restrict__ F,
                                             unsigned char* __restrict__ hist, int* __restrict__ out) {
  __shared__ float sc[2][9][64];
  const float* feats = F + OF_FEATS;
  const float* aux = F + OF_AUX;
  int tid = threadIdx.x;
  int cur = tid >> 6, b = tid & 63;
  float tr[9];
#pragma unroll
  for (int pv = 0; pv < 9; ++pv) tr[pv] = aux[48 + pv * 9 + cur];
  sc[0][cur][b] = aux[16 + cur] + feats[cur * 64 + b];
  __syncthreads();
  int p = 0;
  for (int t = 1; t < 256; ++t) {
    float emit = feats[((size_t)t * 9 + cur) * 64 + b];
    float best = sc[p][0][b] + tr[0]; int ba = 0;
#pragma unroll
    for (int pv = 1; pv < 9; ++pv) {
      float v = sc[p][pv][b] + tr[pv];
      if (v > best) { best = v; ba = pv; }   // strict > keeps FIRST max (jnp.argmax)
    }
    sc[p ^ 1][cur][b] = best + emit;
    hist[((size_t)(t - 1) * 9 + cur) * 64 + b] = (unsigned char)ba;
    p ^= 1;
    __syncthreads();
  }
  __threadfence();
  if (tid < 64) {
    float best = sc[p][0][tid] + aux[32]; int tag = 0;
    for (int cu = 1; cu < 9; ++cu) {
      float v = sc[p][cu][tid] + aux[32 + cu];
      if (v > best) { best = v; tag = cu; }
    }
    out[tid * 256 + 255] = tag;
    for (int pos = 254; pos >= 0; --pos) {
      tag = hist[((size_t)pos * 9 + tag) * 64 + tid];
      out[tid * 256 + pos] = tag;
    }
  }
}

extern "C" void kernel_launch(void* const* d_in, const int* in_sizes, int n_in,
                              void* d_out, int out_size, void* d_ws, size_t ws_size,
                              hipStream_t stream) {
  char* ws = (char*)d_ws;
  int* flag = (int*)ws;
  int* cnt = (int*)(ws + 64);
  float* F = (float*)(ws + 8192);
  unsigned char* hist = (unsigned char*)(F + OF_HIST);

  const int* sent = (const int*)d_in[0];
  // d_in[1] = mask: all-ones, ignored by construction.

  k_probe<<<1, 256, 0, stream>>>(d_in[2], flag, cnt);
  k_prep<<<2048, 256, 0, stream>>>(flag,
      d_in[3], d_in[4], d_in[5], d_in[6],
      d_in[7], d_in[8], d_in[9], d_in[10],
      d_in[11], d_in[12], d_in[13], d_in[14],
      d_in[15], d_in[16], d_in[17], F);
  k_gather<<<4096, 256, 0, stream>>>(flag, sent, d_in[2], F + OF_X32);
  k_gemm<<<2048, 256, 0, stream>>>(F + OF_X32, F + OF_BMAT, F + OF_BIAS, F + OF_XPROJ);
  k_rec<<<2 * WG_PER_DIR, 256, 0, stream>>>(F, F, cnt);
  k_feats<<<256, 256, 0, stream>>>(F, F + OF_FEATS);
  k_vit<<<1, 576, 0, stream>>>(F, hist, (int*)d_out);
}

// Round 5
// 2839.232 us; speedup vs baseline: 1.6184x; 1.1271x over previous
//
#include <hip/hip_runtime.h>

#define DEV __device__ __forceinline__

typedef float nfloat4 __attribute__((ext_vector_type(4)));  // native vec for nontemporal builtins

// Problem dims (fixed)
constexpr int L = 256, NB = 64, E = 256, HH = 256, T = 9;
constexpr int WG_PER_DIR = 64;            // recurrence WGs per direction
constexpr int U_PER_WG = HH / WG_PER_DIR; // 4 units per WG

// ---- workspace layout (float offsets, after 32 KB header) ----
// header: ws+0 dtype flag | ws+1024 producer flags PF[128] (64B stride)
//         ws+9216 superflags SF[32] (64B stride) | ws+32768 F
constexpr size_t OF_BMAT  = 0;                          // [256][2048]  w_ih^T both dirs
constexpr size_t OF_WPK   = OF_BMAT + (size_t)256*2048; // [2][256u][256k][4g]
constexpr size_t OF_BIAS  = OF_WPK + (size_t)2*256*256*4; // [2][256][4]
constexpr size_t OF_CINIT = OF_BIAS + (size_t)2*256*4;  // [2][256u][64b]
constexpr size_t OF_WOUT  = OF_CINIT + (size_t)2*256*64; // [512][12]
constexpr size_t OF_AUX   = OF_WOUT + (size_t)512*12;   // 256: [0..8] b_out, [16..24] start, [32..40] end, [48..128] trans
constexpr size_t OF_X32   = OF_AUX + 256;               // [16384][256] embedded inputs f32
constexpr size_t OF_XPROJ = OF_X32 + (size_t)16384*256; // [2][256t][256u][64b][4g]
constexpr size_t OF_HF    = OF_XPROJ + (size_t)2*256*256*64*4; // [257][256u][64b] slot t+1 = h_f(t), slot0 init
constexpr size_t OF_HB    = OF_HF + (size_t)257*256*64;        // [257], slot t = h_b(t), slot256 init
constexpr size_t OF_FEATS = OF_HB + (size_t)257*256*64; // [256t][9][64]
constexpr size_t OF_HIST  = OF_FEATS + (size_t)256*9*64; // uchar[255][9][64]

// prep segment bounds
constexpr size_t S1 = (size_t)256*2048;        // Bmat
constexpr size_t S2 = S1 + (size_t)2*256*256*4; // w_pk
constexpr size_t S3 = S2 + (size_t)2*256*4;     // bias
constexpr size_t S4 = S3 + (size_t)2*256*64;    // h_init
constexpr size_t S5 = S4 + (size_t)2*256*64;    // c_init
constexpr size_t S6 = S5 + (size_t)512*12;      // w_outP
constexpr size_t S7 = S6 + 256;                 // aux

DEV float b2f(unsigned short u) {
  union { unsigned int i; float f; } c; c.i = ((unsigned int)u) << 16; return c.f;
}
DEV float ldf(const void* p, size_t i, int isb) {
  return isb ? b2f(((const unsigned short*)p)[i]) : ((const float*)p)[i];
}
DEV float sigm(float x) { return 1.0f / (1.0f + expf(-x)); }

// ---- K0: dtype probe + zero sync flags (PF 2048 ints + SF 512 ints) ----
__global__ void k_probe(const void* emb, int* flag, int* pf) {
  int tid = threadIdx.x;
#pragma unroll
  for (int r = 0; r < 10; ++r) pf[r * 256 + tid] = 0;   // 2560 ints: PF + SF regions
  if (tid == 0) {
    const unsigned short* p = (const unsigned short*)emb;
    int bad = 0;
    for (int i = 0; i < 256; ++i) {
      float f = b2f(p[i]);
      if (!(fabsf(f) < 1e6f)) bad = 1;   // NaN/huge -> really fp32 data
    }
    *flag = bad ? 0 : 1;                  // 1 = bf16 inputs
  }
}

// ---- K1: convert/pack all weights to f32 in ws ----
__global__ __launch_bounds__(256) void k_prep(
    const int* __restrict__ flag,
    const void* wihf, const void* whhf, const void* bihf, const void* bhhf,
    const void* wihb, const void* whhb, const void* bihb, const void* bhhb,
    const void* h0, const void* c0, const void* wout, const void* bout,
    const void* st, const void* en, const void* tr, float* __restrict__ F) {
  int isb = *flag;
  for (size_t i = (size_t)blockIdx.x * 256 + threadIdx.x; i < S7; i += (size_t)gridDim.x * 256) {
    if (i < S1) { // Bmat[k][n]: n = dir*1024 + u*4 + g <- w_ih[g*256+u][k]
      size_t k = i >> 11; int n = (int)(i & 2047);
      int dir = n >> 10, r = n & 1023, u = r >> 2, g = r & 3;
      const void* src = dir ? wihb : wihf;
      F[OF_BMAT + i] = ldf(src, (size_t)(g*256 + u)*256 + k, isb);
    } else if (i < S2) { // w_pk[dir][u][k][g] <- w_hh[g*256+u][k]
      size_t j = i - S1; int g = (int)(j & 3); size_t r = j >> 2;
      int k = (int)(r & 255); r >>= 8; int u = (int)(r & 255); int dir = (int)(r >> 8);
      const void* src = dir ? whhb : whhf;
      F[OF_WPK + j] = ldf(src, (size_t)(g*256 + u)*256 + k, isb);
    } else if (i < S3) { // bias_pk[dir][u][g] = b_ih + b_hh
      size_t j = i - S2; int g = (int)(j & 3); size_t r = j >> 2;
      int u = (int)(r & 255); int dir = (int)(r >> 8);
      const void* bi = dir ? bihb : bihf; const void* bh = dir ? bhhb : bhhf;
      F[OF_BIAS + j] = ldf(bi, (size_t)g*256 + u, isb) + ldf(bh, (size_t)g*256 + u, isb);
    } else if (i < S4) { // h init: [u][b] <- h0[dir][b][u]
      size_t j = i - S3; int dir = (int)(j >> 14); int r = (int)(j & 16383);
      int u = r >> 6, b = r & 63;
      float v = ldf(h0, (size_t)dir*16384 + (size_t)b*256 + u, isb);
      if (dir == 0) F[OF_HF + r] = v;               // slot 0
      else          F[OF_HB + (size_t)256*16384 + r] = v; // slot 256
    } else if (i < S5) { // c init
      size_t j = i - S4; int dir = (int)(j >> 14); int r = (int)(j & 16383);
      int u = r >> 6, b = r & 63;
      F[OF_CINIT + j] = ldf(c0, (size_t)dir*16384 + (size_t)b*256 + u, isb);
    } else if (i < S6) { // w_outP[j][tag] (stride 12) <- w_out[tag][j]
      size_t j = i - S5; int jj = (int)(j / 12); int tag = (int)(j % 12);
      F[OF_WOUT + j] = (tag < 9) ? ldf(wout, (size_t)tag*512 + jj, isb) : 0.0f;
    } else { // aux
      int j = (int)(i - S6); float v = 0.0f;
      if (j < 9) v = ldf(bout, j, isb);
      else if (j >= 16 && j < 25) v = ldf(st, j - 16, isb);
      else if (j >= 32 && j < 41) v = ldf(en, j - 32, isb);
      else if (j >= 48 && j < 129) v = ldf(tr, j - 48, isb);
      F[OF_AUX + j] = v;
    }
  }
}

// ---- K2a: embedding gather -> x32[m=(l*64+b)][k] f32 ----
__global__ __launch_bounds__(256) void k_gather(const int* __restrict__ flag,
    const int* __restrict__ sent, const void* __restrict__ emb, float* __restrict__ x32) {
  int isb = *flag;
  int g = blockIdx.x * 256 + threadIdx.x;   // 1,048,576 threads
  int m = g >> 6, q = g & 63;
  int l = m >> 6, b = m & 63;
  int row = sent[b * 256 + l];
  float4 v;
  if (isb) {
    const ushort4 s4 = ((const ushort4*)emb)[(size_t)row * 64 + q];
    v.x = b2f(s4.x); v.y = b2f(s4.y); v.z = b2f(s4.z); v.w = b2f(s4.w);
  } else {
    v = ((const float4*)emb)[(size_t)row * 64 + q];
  }
  ((float4*)x32)[(size_t)m * 64 + q] = v;
}

// ---- K2b: xproj GEMM  M=16384 N=2048 K=256 (f32), epilogue scatters to [t][u][b][g] + bias ----
__global__ __launch_bounds__(256) void k_gemm(const float* __restrict__ x32,
    const float* __restrict__ Bm, const float* __restrict__ biasPk, float* __restrict__ xproj) {
  __shared__ float As[8][128];
  __shared__ float Bs[8][128];
  int tid = threadIdx.x;
  int mTile = blockIdx.x >> 4, nTile = blockIdx.x & 15;
  int mBase = mTile * 128, nBase = nTile * 128;
  int ty = tid >> 4, tx = tid & 15;
  int ar = tid >> 1, ac = (tid & 1) * 4;
  int br = tid >> 5, bc = (tid & 31) * 4;
  float acc[8][8] = {};
  for (int k0 = 0; k0 < 256; k0 += 8) {
    float4 av = *(const float4*)(x32 + (size_t)(mBase + ar) * 256 + k0 + ac);
    float4 bv = *(const float4*)(Bm + (size_t)(k0 + br) * 2048 + nBase + bc);
    __syncthreads();
    As[ac + 0][ar] = av.x; As[ac + 1][ar] = av.y; As[ac + 2][ar] = av.z; As[ac + 3][ar] = av.w;
    *(float4*)&Bs[br][bc] = bv;
    __syncthreads();
#pragma unroll
    for (int kk = 0; kk < 8; ++kk) {
      float4 a0 = *(const float4*)&As[kk][ty * 8];
      float4 a1 = *(const float4*)&As[kk][ty * 8 + 4];
      float4 b0 = *(const float4*)&Bs[kk][tx * 8];
      float4 b1 = *(const float4*)&Bs[kk][tx * 8 + 4];
      float a[8] = {a0.x,a0.y,a0.z,a0.w,a1.x,a1.y,a1.z,a1.w};
      float bb[8] = {b0.x,b0.y,b0.z,b0.w,b1.x,b1.y,b1.z,b1.w};
#pragma unroll
      for (int i = 0; i < 8; ++i)
#pragma unroll
        for (int j = 0; j < 8; ++j) acc[i][j] = fmaf(a[i], bb[j], acc[i][j]);
    }
  }
  // epilogue: n = nBase+tx*8+j ; dir = n>>10 ; u = (n&1023)>>2 ; g = n&3
  int n0 = nBase + tx * 8;
  int dir = n0 >> 10, r0 = n0 & 1023, u0 = r0 >> 2;
  float4 bias0 = *(const float4*)(biasPk + (size_t)(dir * 256 + u0) * 4);
  float4 bias1 = *(const float4*)(biasPk + (size_t)(dir * 256 + u0 + 1) * 4);
  float* xp = xproj + ((size_t)dir << 24);
  for (int mm = 0; mm < 8; ++mm) {
    int m = mBase + ty * 8 + mm; int t = m >> 6, b = m & 63;
    float4 v0 = {acc[mm][0] + bias0.x, acc[mm][1] + bias0.y, acc[mm][2] + bias0.z, acc[mm][3] + bias0.w};
    float4 v1 = {acc[mm][4] + bias1.x, acc[mm][5] + bias1.y, acc[mm][6] + bias1.z, acc[mm][7] + bias1.w};
    *(float4*)(xp + ((size_t)(t * 256 + u0) * 64 + b) * 4) = v0;
    *(float4*)(xp + ((size_t)(t * 256 + u0 + 1) * 64 + b) * 4) = v1;
  }
}

// ---- K3: persistent BiLSTM recurrence. 128 WGs: dir = blk>>6, 4 units each.
// Sync topology (anti-contention): producer flags PF are one 64B line per WG;
// aggregator WG (wg==0 per dir) wave0 watches all 64 PF lines (1 lane : 1 line),
// then publishes 16 replicated superflags SF (16 lines); every other WG polls
// ONE SF replica with ONE lane. Total poll lanes ~190 over ~96 lines (was 8192
// over ~8 lines) -> no same-line serialization at the coherence point.
// h published via agent-scope relaxed atomic store (write-through, drained by
// pre-barrier vmcnt(0)); staging via plain nontemporal vec4 (pipelined; h slot
// lines are first-touched only after data is final at the IF).
__global__ __launch_bounds__(256) void k_rec(const float* __restrict__ F,
                                             float* __restrict__ Fm,
                                             int* __restrict__ pf,
                                             int* __restrict__ sf) {
  __shared__ __align__(16) float lds_h[16384];   // h_prev [u 0..255][b 0..63]
  int tid = threadIdx.x;
  int blk = blockIdx.x;
  int dir = blk >> 6, wg = blk & 63;
  int u_local = tid >> 6, b = tid & 63;
  int u = wg * U_PER_WG + u_local;
  int uu = __builtin_amdgcn_readfirstlane(u);    // wave-uniform -> scalar loads of w

  const float* wrow = F + OF_WPK + ((size_t)(dir * 256 + uu)) * 1024; // [k][4]
  const float* xpd  = F + OF_XPROJ + ((size_t)dir << 24);
  float* hall = Fm + (dir == 0 ? OF_HF : OF_HB);
  int* myPF = pf + dir * 1024;                   // PF[w] at myPF[w*16] (64B stride)
  int* mySF = sf + dir * 256;                    // SF[c] at mySF[c*16] (64B stride)

  float c = F[OF_CINIT + (size_t)dir * 16384 + u * 64 + b];

  for (int i = 0; i < 256; ++i) {
    int t = (dir == 0) ? i : (255 - i);
    const float* hsrc = hall + (size_t)((dir == 0) ? i : (t + 1)) * 16384;
    float* hdst = hall + (size_t)((dir == 0) ? (i + 1) : t) * 16384;

    // issue xproj load for this step BEFORE the poll -> HBM latency hides
    float4 acc = *(const float4*)(xpd + ((size_t)(t * 256 + uu) * 64 + b) * 4);

    if (i > 0) {
      if (wg == 0) {
        // aggregator: wave 0, one lane per producer flag line
        if (tid < 64) {
          long spins = 0;
          for (;;) {
            int v = __hip_atomic_load(&myPF[tid * 16], __ATOMIC_RELAXED, __HIP_MEMORY_SCOPE_AGENT);
            if (__ballot(v >= i) == ~0ULL) break;
            __builtin_amdgcn_s_sleep(1);
            if (++spins > (1L << 20)) break;     // safety valve
          }
          if (tid < 16)                          // same wave: publish 16 SF replicas
            __hip_atomic_store(&mySF[tid * 16], i, __ATOMIC_RELAXED, __HIP_MEMORY_SCOPE_AGENT);
        }
      } else {
        if (tid == 0) {                          // single lane polls one SF replica
          long spins = 0;
          while (__hip_atomic_load(&mySF[(wg & 15) * 16], __ATOMIC_RELAXED, __HIP_MEMORY_SCOPE_AGENT) < i) {
            __builtin_amdgcn_s_sleep(2);
            if (++spins > (1L << 20)) break;     // safety valve
          }
        }
      }
      __syncthreads();
    }
    // stage h_prev into LDS: plain nontemporal vec4 (16/thread, pipelined)
    {
      const nfloat4* hs4 = (const nfloat4*)hsrc;
      nfloat4* ls4 = (nfloat4*)lds_h;
#pragma unroll
      for (int r = 0; r < 16; ++r) {
        int idx = r * 256 + tid;
        ls4[idx] = __builtin_nontemporal_load(&hs4[idx]);
      }
    }
    __syncthreads();

    // gates = xproj + h_prev @ w_hh^T  (i,f,g,o packed as float4 per k)
#pragma unroll 8
    for (int k = 0; k < 256; ++k) {
      float hv = lds_h[k * 64 + b];
      float4 w4 = *(const float4*)(wrow + k * 4);
      acc.x = fmaf(hv, w4.x, acc.x);
      acc.y = fmaf(hv, w4.y, acc.y);
      acc.z = fmaf(hv, w4.z, acc.z);
      acc.w = fmaf(hv, w4.w, acc.w);
    }
    c = sigm(acc.y) * c + sigm(acc.x) * tanhf(acc.z);
    float h = sigm(acc.w) * tanhf(c);
    // coherent publish of h (write-through to coherence point)
    __hip_atomic_store(&hdst[u * 64 + b], h, __ATOMIC_RELAXED, __HIP_MEMORY_SCOPE_AGENT);

    if (i < 255) {
      __syncthreads();  // s_waitcnt vmcnt(0) before s_barrier: all 256 h-stores acked
      if (tid == 0)
        __hip_atomic_store(&myPF[wg * 16], i + 1, __ATOMIC_RELAXED, __HIP_MEMORY_SCOPE_AGENT);
    }
  }
}

// ---- K4: feats[t][tag][b] = [hf(t), hb(t)] @ w_out^T + b_out ----
__global__ __launch_bounds__(256) void k_feats(const float* __restrict__ F, float* __restrict__ feats) {
  __shared__ float part[4][9][64];
  int t = blockIdx.x;
  int tid = threadIdx.x;
  int w = tid >> 6, b = tid & 63;
  const float* hsrc = (w < 2) ? (F + OF_HF + (size_t)(t + 1) * 16384)
                              : (F + OF_HB + (size_t)t * 16384);
  int ubase = (w & 1) * 128;
  int jglob0 = (w >> 1) * 256;
  float acc[9] = {};
  for (int jj = 0; jj < 128; ++jj) {
    int u = ubase + jj;
    float hv = hsrc[u * 64 + b];
    int j = __builtin_amdgcn_readfirstlane(jglob0 + u);
    const float* wp = F + OF_WOUT + (size_t)j * 12;
#pragma unroll
    for (int tag = 0; tag < 9; ++tag) acc[tag] = fmaf(hv, wp[tag], acc[tag]);
  }
#pragma unroll
  for (int tag = 0; tag < 9; ++tag) part[w][tag][b] = acc[tag];
  __syncthreads();
  for (int idx = tid; idx < 576; idx += 256) {
    int tag = idx >> 6, bb = idx & 63;
    float s = part[0][tag][bb] + part[1][tag][bb] + part[2][tag][bb] + part[3][tag][bb]
            + F[OF_AUX + tag];
    feats[((size_t)t * 9 + tag) * 64 + bb] = s;
  }
}

// ---- K5: CRF Viterbi decode (mask all-ones). 1 WG, 9 waves: wave=cur tag, lane=b ----
__global__ __launch_bounds__(576) void k_vit(const float* __restrict__ F,
                                             unsigned char* __restrict__ hist, int* __restrict__ out) {
  __shared__ float sc[2][9][64];
  const float* feats = F + OF_FEATS;
  const float* aux = F + OF_AUX;
  int tid = threadIdx.x;
  int cur = tid >> 6, b = tid & 63;
  float tr[9];
#pragma unroll
  for (int pv = 0; pv < 9; ++pv) tr[pv] = aux[48 + pv * 9 + cur];
  sc[0][cur][b] = aux[16 + cur] + feats[cur * 64 + b];
  __syncthreads();
  int p = 0;
  for (int t = 1; t < 256; ++t) {
    float emit = feats[((size_t)t * 9 + cur) * 64 + b];
    float best = sc[p][0][b] + tr[0]; int ba = 0;
#pragma unroll
    for (int pv = 1; pv < 9; ++pv) {
      float v = sc[p][pv][b] + tr[pv];
      if (v > best) { best = v; ba = pv; }   // strict > keeps FIRST max (jnp.argmax)
    }
    sc[p ^ 1][cur][b] = best + emit;
    hist[((size_t)(t - 1) * 9 + cur) * 64 + b] = (unsigned char)ba;
    p ^= 1;
    __syncthreads();
  }
  __threadfence();
  if (tid < 64) {
    float best = sc[p][0][tid] + aux[32]; int tag = 0;
    for (int cu = 1; cu < 9; ++cu) {
      float v = sc[p][cu][tid] + aux[32 + cu];
      if (v > best) { best = v; tag = cu; }
    }
    out[tid * 256 + 255] = tag;
    for (int pos = 254; pos >= 0; --pos) {
      tag = hist[((size_t)pos * 9 + tag) * 64 + tid];
      out[tid * 256 + pos] = tag;
    }
  }
}

extern "C" void kernel_launch(void* const* d_in, const int* in_sizes, int n_in,
                              void* d_out, int out_size, void* d_ws, size_t ws_size,
                              hipStream_t stream) {
  char* ws = (char*)d_ws;
  int* flag = (int*)ws;
  int* pf = (int*)(ws + 1024);          // producer flags: 128 x 64B
  int* sf = pf + 2048;                  // superflags: 32 x 64B (at ws+9216)
  float* F = (float*)(ws + 32768);
  unsigned char* hist = (unsigned char*)(F + OF_HIST);

  const int* sent = (const int*)d_in[0];
  // d_in[1] = mask: all-ones, ignored by construction.

  k_probe<<<1, 256, 0, stream>>>(d_in[2], flag, pf);
  k_prep<<<2048, 256, 0, stream>>>(flag,
      d_in[3], d_in[4], d_in[5], d_in[6],
      d_in[7], d_in[8], d_in[9], d_in[10],
      d_in[11], d_in[12], d_in[13], d_in[14],
      d_in[15], d_in[16], d_in[17], F);
  k_gather<<<4096, 256, 0, stream>>>(flag, sent, d_in[2], F + OF_X32);
  k_gemm<<<2048, 256, 0, stream>>>(F + OF_X32, F + OF_BMAT, F + OF_BIAS, F + OF_XPROJ);
  k_rec<<<2 * WG_PER_DIR, 256, 0, stream>>>(F, F, pf, sf);
  k_feats<<<256, 256, 0, stream>>>(F, F + OF_FEATS);
  k_vit<<<1, 576, 0, stream>>>(F, hist, (int*)d_out);
}